// Round 8
// baseline (154.707 us; speedup 1.0000x reference)
//
#include <hip/hip_runtime.h>
#include <string.h>

// Integer-quantized MHA. R14: phase 1 switched from exact-int i8 DIGIT GEMM to
// native bf16 MFMA. Rationale: dequantized K/Q values m<<s have <=8 significant
// bits -> exact in bf16 (same trick phase 2 uses for vt); products <=15 sig
// bits exact in f32; score magnitudes (sigma~1.3e6) never reach the 2^24
// f32-exact limit with this input distribution (>12-sigma). Effects:
//  - phase-1 MFMA count HALVES (8x i8 16x16x64 -> 4x bf16 16x16x32 per tile),
//    same staged bytes (bf16 plane = 2B/elem = the two digit planes).
//  - digit recombine (a2<<8)+(a1<<4)+a0 (192 VALU/thread) deleted; MFMA
//    accumulator IS scv.
//  - Q build: plain 32-int->bf16 pack (~40 ops vs ~100 for dig16 x2).
//  - softmax back to float-domain max (scores are exact ints in f32; the
//    subtract is exact) -- bit-equivalent to R13's int-max path.
// Kept from R13/R11: transposed phase 1 (C[s][t], quant group lane-local),
// 32KB LDS block, XOR col swizzle (store 4/bank, read 8/bank), reduction
// scratch carved into rbuf row 15, barrier structure, phase 2 unchanged.
// History: R11/R13 = 61.8-62.6us mha; TT=32 closed (R9 spill, R12 occupancy);
// LDS conflicts & occupancy axes closed (R4/R7 null results).
// B=2,H=16 (BH=32), T=S=1024, HC=128, G=8. Output int32.

typedef int   v4i __attribute__((ext_vector_type(4)));
typedef float v4f __attribute__((ext_vector_type(4)));
typedef short v8s __attribute__((ext_vector_type(8)));
typedef unsigned v2u __attribute__((ext_vector_type(2)));

#define BHN 32
#define TN  1024
#define SN  1024
#define HCN 128
#define TT  16
#define KD_BH 262144           // 8 ch * 8 n * 4 kc * 64 lanes * 16 B (bf16 frags)
#define VD_BH 262144           // 32 kb * 8 n * 64 lanes * 16 B (bf16 frags)
#define WS_NEED ((size_t)BHN*(KD_BH+VD_BH))   // 16 MB

__device__ __forceinline__ unsigned short bf16_of_int(int v){
    return (unsigned short)(__float_as_uint((float)v) >> 16);   // exact: <=8 sig bits
}

// pack 8 consecutive dequantized ints (one scale group) into 4 bf16x2 words
__device__ __forceinline__ v4i pack8(const int* __restrict__ p, int s){
    unsigned wd[4];
    #pragma unroll
    for (int j=0;j<4;j++){
        int a = p[j*2]   << s;
        int b = p[j*2+1] << s;
        wd[j] = (unsigned)bf16_of_int(a) | ((unsigned)bf16_of_int(b) << 16);
    }
    return v4i{(int)wd[0],(int)wd[1],(int)wd[2],(int)wd[3]};
}

// ---------------- pre-pass (gather form: coalesced stores) ----------------
// kd: per bh, [ch(8)][n(8)][kc(4)][lane64][16B] bf16 A-frags (K=32 chunks):
//     lane q4*16+l15 holds K[row=n*16+l15][c = kc*32 + q4*8 + 0..7].
// vd: per bh, [kb(32)][n(8)][lane64][16B] bf16 B-frags (unchanged).
// One wave per fragment tile: lane stores base+lane*16 -> 1KB wave-stores.
// Tasks: 0..8191 = kd (bh*256+ch*32+n*4+kc); 8192..16383 = vd (bh*256+kb*8+n).
__global__ __launch_bounds__(256) void digitize(
    const int* __restrict__ k_q, const int* __restrict__ k_s,
    const int* __restrict__ vt_q, const int* __restrict__ vt_s,
    unsigned char* __restrict__ kd, unsigned char* __restrict__ vd)
{
    const int w    = threadIdx.x >> 6;
    const int lane = threadIdx.x & 63;
    const int l15  = lane & 15;
    const int q4   = lane >> 4;
    const int task = blockIdx.x*4 + w;
    if (task < 8192){
        const int kc = task & 3, n = (task>>2)&7, ch = (task>>5)&7, bh = task>>8;
        const int row = bh*SN + ch*128 + n*16 + l15;
        const int col = kc*32 + q4*8;
        v4i f = pack8(k_q + (size_t)row*HCN + col, k_s[row*16 + (col>>3)]);
        size_t base = (size_t)bh*KD_BH + (size_t)((((ch*8+n)*4 + kc)*64 + lane)*16);
        *(v4i*)(kd + base) = f;             // 1KB coalesced wave store
    } else {
        const int t  = task - 8192;
        const int n  = t & 7, kb = (t>>3)&31, bh = t>>8;
        const int row = bh*HCN + n*16 + l15;       // vt channel row
        v4i f = pack8(vt_q + (size_t)row*SN + kb*32 + q4*8,
                      vt_s[row*128 + kb*4 + q4]);
        size_t base = (size_t)bh*VD_BH + (size_t)(((kb*8 + n)*64 + lane)*16);
        *(v4i*)(vd + base) = f;
    }
}

// ---------------- main fused kernel ----------------
template<bool PK>
__global__ __launch_bounds__(256,4) void mha_mfma(
    const int* __restrict__ q_q, const int* __restrict__ q_s,
    const int* __restrict__ k_q, const int* __restrict__ k_s,
    const int* __restrict__ vt_q, const int* __restrict__ vt_s,
    const unsigned char* __restrict__ kd, const unsigned char* __restrict__ vd,
    int* __restrict__ out)
{
    // EXACTLY 32 KB (R13 artifact).
    __shared__ __align__(16) unsigned short rbuf[16*1024];
    // reduction scratch carved into rbuf row 15 cols 768..1023 (dead until
    // requant, which overwrites it only after bar3).
    float* redm = (float*)(rbuf + 16128);   // 64 floats: row-max partials
    float* redf = (float*)(rbuf + 16256);   // 64 floats: row-sum partials

    const int tid  = threadIdx.x;
    const int ln   = tid & 15;
    const int qd4  = (tid >> 4) & 3;
    const int w    = tid >> 6;
    const int lane = tid & 63;
    // XCD-aware swizzle: each XCD's share covers only 4 bh -> digit images fit its L2.
    const int blk = blockIdx.x;
    const int bh  = ((blk>>9)<<3) | (blk&7);
    const int t0  = ((blk>>3)&63) * TT;

    // ---- Q fragments in registers (B operand in phase 1, t=ln), bf16 exact ----
    v8s qf[4];
    {
        const int* qrow = q_q + (size_t)(bh*TN + t0 + ln)*HCN;
        const int* qs   = q_s + (size_t)(bh*TN + t0 + ln)*16;
        #pragma unroll
        for (int kc=0; kc<4; ++kc){
            int col = kc*32 + qd4*8;
            v4i t = pack8(qrow + col, qs[col>>3]);
            memcpy(&qf[kc], &t, 16);
        }
    }

    v4f scv[16];   // C[s][t]: s = (ch*8 + w*2 + i)*16 + qd4*4 + r, t = ln
                   // values are EXACT integer scores in f32 (see header)

    // ========== phase 1: QK^T scores, transposed bf16 MFMA (barrier-free) ==========
    const v4i* kb_ = (const v4i*)(kd + (size_t)bh*KD_BH);
    for (int ch=0; ch<8; ++ch){
        #pragma unroll
        for (int i=0;i<2;i++){
            const int n = w*2 + i;
            v4f acc{0.f,0.f,0.f,0.f};
            #pragma unroll
            for (int kc=0;kc<4;kc++){
                v8s af;
                if (PK){
                    v4i a_ = kb_[((ch*8+n)*4 + kc)*64 + lane];
                    memcpy(&af, &a_, 16);
                } else {
                    int srow = bh*SN + ch*128 + n*16 + ln;
                    int cc   = kc*32 + qd4*8;
                    v4i a_ = pack8(k_q + (size_t)srow*HCN + cc,
                                   k_s[srow*16 + (cc>>3)]);
                    memcpy(&af, &a_, 16);
                }
                // A = K frag, B = Q frag  ->  C[s][t]
                acc = __builtin_amdgcn_mfma_f32_16x16x32_bf16(af, qf[kc], acc, 0,0,0);
            }
            scv[ch*2 + i] = acc;
        }
    }

    // ================= softmax over s (float max, log2-domain exp) =================
    // Thread's 64 elements belong to ONE output row t=ln. Scores are exact ints
    // in f32; (s - m) is an exact subtraction at these magnitudes.
    const float CS2 = (float)(6.103515625e-05 / 11.313708498984760390566
                              * 1.4426950408889634074);
    {
        float m0=-3.0e38f, m1=-3.0e38f, m2=-3.0e38f, m3=-3.0e38f;
        #pragma unroll
        for (int st=0;st<16;st++){
            m0 = fmaxf(m0, scv[st][0]);
            m1 = fmaxf(m1, scv[st][1]);
            m2 = fmaxf(m2, scv[st][2]);
            m3 = fmaxf(m3, scv[st][3]);
        }
        float m_ = fmaxf(fmaxf(m0,m1), fmaxf(m2,m3));
        m_ = fmaxf(m_, __shfl_xor(m_, 16));
        m_ = fmaxf(m_, __shfl_xor(m_, 32));
        if ((tid & 48) == 0) redm[w*16 + ln] = m_;
    }
    __syncthreads();                                  // bar1: redm visible
    float inv14;
    {
        const float mrow = fmaxf(fmaxf(redm[ln], redm[16+ln]),
                                 fmaxf(redm[32+ln], redm[48+ln]));
        float s0=0.f, s1=0.f, s2=0.f, s3=0.f;
        #pragma unroll
        for (int st=0;st<16;st++){
            #pragma unroll
            for (int r=0;r<4;r++){
                float t_ = (scv[st][r] - mrow) * CS2;          // <= 0, sub exact
                float e;
                asm("v_exp_f32 %0, %1" : "=v"(e) : "v"(t_));   // 2^t
                scv[st][r] = e;
                if (r==0) s0 += e; else if (r==1) s1 += e; else if (r==2) s2 += e; else s3 += e;
            }
        }
        float s_ = (s0+s1) + (s2+s3);
        s_ += __shfl_xor(s_, 16);
        s_ += __shfl_xor(s_, 32);
        if ((tid & 48) == 0) redf[w*16 + ln] = s_;
    }
    __syncthreads();                                  // bar2: redf visible
    {
        float sum = redf[ln] + redf[16+ln] + redf[32+ln] + redf[48+ln];
        inv14 = 16384.0f / sum;        // one IEEE div per thread
    }
    __syncthreads();                                  // bar3: sum-reads done before
                                                      // requant overwrites row 15

    // ======== group-of-8 po2 requant, in registers -> b64 rbuf stores ========
    // granule = thread's 4 s-values + partner at lane^16; gmax <= 255<<sh so no clamp.
    // XOR swizzle c' = c ^ ((ln&7)<<4) on unpadded 2048B rows (R13-validated):
    // store 4/bank, read 8/bank, bijective, 8-aligned runs stay contiguous.
    {
        const int lnr4 = (ln & 7) << 4;
        const int cbase = w*32 + qd4*4;
        unsigned short* rp = rbuf + ln*1024;
        #pragma unroll
        for (int st=0;st<16;st++){
            float v0 = rintf(scv[st][0] * inv14);
            float v1 = rintf(scv[st][1] * inv14);
            float v2 = rintf(scv[st][2] * inv14);
            float v3 = rintf(scv[st][3] * inv14);
            float g = fmaxf(fmaxf(v0,v1), fmaxf(v2,v3));
            g = fmaxf(g, __shfl_xor(g, 16));            // partner half of the granule
            int gi = max((int)g, 1);
            int x  = gi - 1;
            int e2 = 31 - __clz(x | 255);
            int sh = (e2 - 7) + ((x >> (e2 - 7)) == 255); // clip(ceil(log2(gi/255)),0,)
            float isc = __int_as_float((127 - sh) << 23); // exact 2^-sh
            float fsc = __int_as_float((127 + sh) << 23); // exact 2^sh
            unsigned b0 = __float_as_uint(rintf(v0*isc) * fsc);  // r = rq<<sh, 8 sig bits
            unsigned b1 = __float_as_uint(rintf(v1*isc) * fsc);
            unsigned b2 = __float_as_uint(rintf(v2*isc) * fsc);
            unsigned b3 = __float_as_uint(rintf(v3*isc) * fsc);
            unsigned w0 = __builtin_amdgcn_perm(b1, b0, 0x07060302u); // {bf16(v0),bf16(v1)}
            unsigned w1 = __builtin_amdgcn_perm(b3, b2, 0x07060302u);
            int c0 = (st>>1)*128 + cbase + (st&1)*16;   // col of v0 (u16 units, 4-aligned)
            *(v2u*)(rp + (c0 ^ lnr4)) = v2u{w0, w1};    // one swizzled b64 store per tile
        }
    }
    __syncthreads();                                  // bar4: rbuf ready

    // ================= phase 2: out = r @ vt^T (bf16 MFMA, barrier-free) =================
    const v4i* vb = (const v4i*)(vd + (size_t)bh*VD_BH);
    const unsigned short* rp2 = rbuf + ln*1024;
    const int lnr4b = (ln & 7) << 4;
    v4f acc0{0,0,0,0}, acc1{0,0,0,0};
    #pragma unroll 4
    for (int kb=0; kb<32; ++kb){
        // A frag: r[t=ln][s = kb*32 + qd4*8 + j], 8 bf16 = one b128 from LDS
        v8s af = *(const v8s*)(rp2 + ((kb*32 + qd4*8) ^ lnr4b));
        v4i b0, b1;
        if (PK){
            b0 = vb[(kb*8 + w*2    )*64 + lane];
            b1 = vb[(kb*8 + w*2 + 1)*64 + lane];
        } else {
            #pragma unroll
            for (int i=0;i<2;i++){
                int chan = (w*2+i)*16 + ln;
                v4i t = pack8(vt_q + (size_t)(bh*HCN + chan)*SN + kb*32 + qd4*8,
                              vt_s[(bh*HCN + chan)*128 + kb*4 + qd4]);
                if (i==0) b0 = t; else b1 = t;
            }
        }
        v8s bs0, bs1;
        memcpy(&bs0, &b0, 16);
        memcpy(&bs1, &b1, 16);
        acc0 = __builtin_amdgcn_mfma_f32_16x16x32_bf16(af, bs0, acc0, 0,0,0);
        acc1 = __builtin_amdgcn_mfma_f32_16x16x32_bf16(af, bs1, acc1, 0,0,0);
    }
    #pragma unroll
    for (int r=0;r<4;r++){
        size_t o = (size_t)(bh*TN + t0 + qd4*4 + r)*HCN + w*32 + ln;
        out[o]      = (int)rintf(acc0[r]);
        out[o + 16] = (int)rintf(acc1[r]);
    }
}

extern "C" void kernel_launch(void* const* d_in, const int* in_sizes, int n_in,
                              void* d_out, int out_size, void* d_ws, size_t ws_size,
                              hipStream_t stream) {
    const int* q_q  = (const int*)d_in[0];
    const int* q_s  = (const int*)d_in[1];
    const int* k_q  = (const int*)d_in[2];
    const int* k_s  = (const int*)d_in[3];
    const int* vt_q = (const int*)d_in[4];
    const int* vt_s = (const int*)d_in[5];
    int* out = (int*)d_out;

    unsigned char* kd = (unsigned char*)d_ws;
    unsigned char* vd = kd + (size_t)BHN*KD_BH;

    if (ws_size >= WS_NEED){
        // 16384 wave-tasks (8192 kd + 8192 vd), 4 waves/block
        digitize<<<dim3(4096), 256, 0, stream>>>(k_q,k_s,vt_q,vt_s, kd,vd);
        mha_mfma<true><<<dim3(2048), 256, 0, stream>>>(
            q_q,q_s,k_q,k_s,vt_q,vt_s, kd,vd, out);
    } else {
        mha_mfma<false><<<dim3(2048), 256, 0, stream>>>(
            q_q,q_s,k_q,k_s,vt_q,vt_s, kd,vd, out);
    }
}

// Round 9
// 150.654 us; speedup vs baseline: 1.0269x; 1.0269x over previous
//
#include <hip/hip_runtime.h>
#include <string.h>

// Integer-quantized MHA. Phase 1: exact-int i8 K=64 MFMA digit GEMM, TRANSPOSED
// (C[s][t] via mfma(K,Q)). Phase 2: native bf16 MFMA.
// R16 = R13 artifact (61.8us known-good) + SOFTWARE PREFETCH (the R14 lesson:
// phase 1 is load-latency-bound; halving its compute-per-load made it SLOWER
// (72.5us, VALU 40->28%, MFMA 16->9%, stall +45k cyc). VGPR=52 proved the
// compiler does zero cross-iteration prefetch under the (256,4) 128-reg cap).
//  - __launch_bounds__(256,3): matches MEASURED occupancy (12-13 waves/CU);
//    raises VGPR cap to 170 for prefetch buffers.
//  - phase 1: tile ping-pong -- prefetch tile t+1's 4 kd fragments during
//    tile t's 8 MFMAs+recombine (~180cyc cover vs ~200cyc L2 latency).
//  - phase 2: group-of-4 ping-pong (8 vd loads + 4 LDS reads ahead); group-0
//    vd loads HOISTED above requant (T14: latency hides under requant VALU).
//  - arithmetic/layout/swizzle/barriers/digitize bit-identical to R13.
// Closed axes: TT=32 (R9 spill, R12 occupancy), LDS conflicts (R4/R5 null),
// LDS-size occupancy (R7 null), bf16 phase-1 (R14 regression).
// B=2,H=16 (BH=32), T=S=1024, HC=128, G=8. Output int32.

typedef int   v4i __attribute__((ext_vector_type(4)));
typedef float v4f __attribute__((ext_vector_type(4)));
typedef short v8s __attribute__((ext_vector_type(8)));
typedef unsigned v2u __attribute__((ext_vector_type(2)));

#define BHN 32
#define TN  1024
#define SN  1024
#define HCN 128
#define TT  16
#define KD_BH 262144           // 8 chunks * 32 KB (2 planes, fragment-ordered)
#define VD_BH 262144           // 32 kb * 8 n * 64 lanes * 16 B (bf16 frags)
#define WS_NEED ((size_t)BHN*(KD_BH+VD_BH))   // 16 MB

__device__ __forceinline__ unsigned pack_b(int b0,int b1,int b2,int b3){
    return (unsigned)((b0&255)|((b1&255)<<8)|((b2&255)<<16)|((b3&255)<<24));
}

// digitize 16 consecutive dequantized ints (2 scale groups) into hi/lo i8 digit vectors
__device__ __forceinline__ void dig16(const int* __restrict__ p, int s0, int s1,
                                      v4i& hi, v4i& lo){
    #pragma unroll
    for (int wi=0; wi<4; ++wi){
        v4i m = *(const v4i*)(p + wi*4);
        int s = (wi<2) ? s0 : s1;
        int d0=m[0]<<s, d1=m[1]<<s, d2=m[2]<<s, d3=m[3]<<s;
        hi[wi] = (int)pack_b(d0>>4,d1>>4,d2>>4,d3>>4);
        lo[wi] = (int)pack_b(d0&15,d1&15,d2&15,d3&15);
    }
}

__device__ __forceinline__ unsigned short bf16_of_int(int v){
    return (unsigned short)(__float_as_uint((float)v) >> 16);   // exact: <=8 sig bits
}

// ---------------- pre-pass (gather form: coalesced stores) ----------------
// kd: per bh, [ch(8)][n(8)][kc(2)][plane(2:hi,lo)][lane64][16B]
// vd: per bh, [kb(32)][n(8)][lane64][16B]  (8 bf16 per lane)
// One wave per fragment tile: wave stores lane*16 -> contiguous 1KB per store.
// Tasks: 0..4095 = kd (bh*128+ch*16+n*2+kc); 4096..12287 = vd (bh*256+kb*8+n).
__global__ __launch_bounds__(256) void digitize(
    const int* __restrict__ k_q, const int* __restrict__ k_s,
    const int* __restrict__ vt_q, const int* __restrict__ vt_s,
    unsigned char* __restrict__ kd, unsigned char* __restrict__ vd)
{
    const int w    = threadIdx.x >> 6;
    const int lane = threadIdx.x & 63;
    const int l15  = lane & 15;
    const int task = blockIdx.x*4 + w;
    if (task < 4096){
        const int kc = task & 1, n = (task>>1)&7, ch = (task>>4)&7, bh = task>>7;
        const int q4   = lane >> 4;
        const int srow = bh*SN + ch*128 + n*16 + l15;
        const int gb   = srow*16 + kc*8 + q4*2;
        v4i hi, lo;
        dig16(k_q + (size_t)srow*HCN + kc*64 + q4*16, k_s[gb], k_s[gb+1], hi, lo);
        size_t base = (size_t)bh*KD_BH + (size_t)(ch*32768 + n*4096 + kc*2048 + lane*16);
        *(v4i*)(kd + base)        = hi;     // 1KB coalesced wave store (hi plane)
        *(v4i*)(kd + base + 1024) = lo;     // 1KB coalesced wave store (lo plane)
    } else {
        const int t  = task - 4096;
        const int n  = t & 7, kb = (t>>3)&31, bh = t>>8;
        const int sub = lane >> 4;                 // s-quad within fragment
        const int row = bh*HCN + n*16 + l15;       // vt channel row
        const int* vp = vt_q + (size_t)row*SN + kb*32 + sub*8;
        const int s   = vt_s[row*128 + kb*4 + sub];
        unsigned wds[4];
        #pragma unroll
        for (int j=0;j<4;j++){
            int a = vp[j*2]   << s;
            int b = vp[j*2+1] << s;
            wds[j] = (unsigned)bf16_of_int(a) | ((unsigned)bf16_of_int(b) << 16);
        }
        size_t base = (size_t)bh*VD_BH + (size_t)(((kb*8 + n)*64 + lane)*16);
        *(v4i*)(vd + base) = v4i{(int)wds[0],(int)wds[1],(int)wds[2],(int)wds[3]};
    }
}

// ---------------- main fused kernel ----------------
template<bool PK>
__global__ __launch_bounds__(256,3) void mha_mfma(
    const int* __restrict__ q_q, const int* __restrict__ q_s,
    const int* __restrict__ k_q, const int* __restrict__ k_s,
    const int* __restrict__ vt_q, const int* __restrict__ vt_s,
    const unsigned char* __restrict__ kd, const unsigned char* __restrict__ vd,
    int* __restrict__ out)
{
    // EXACTLY 32 KB (R13 artifact).
    __shared__ __align__(16) unsigned short rbuf[16*1024];
    // reduction scratch carved into rbuf row 15 cols 768..1023 (dead until
    // requant, which overwrites it only after bar3).
    int*   redi = (int*)  (rbuf + 16128);   // 64 ints   (row15 cols 768..895)
    float* redf = (float*)(rbuf + 16256);   // 64 floats (row15 cols 896..1023)

    const int tid  = threadIdx.x;
    const int ln   = tid & 15;
    const int qd4  = (tid >> 4) & 3;
    const int w    = tid >> 6;
    const int lane = tid & 63;
    // XCD-aware swizzle: each XCD's share covers only 4 bh -> digit images fit its L2.
    const int blk = blockIdx.x;
    const int bh  = ((blk>>9)<<3) | (blk&7);
    const int t0  = ((blk>>3)&63) * TT;

    // ---- Q fragments in registers (B operand in phase 1, t=ln) ----
    v4i qfh[2], qfl[2];
    {
        const int* qrow  = q_q + (size_t)(bh*TN + t0 + ln)*HCN;
        const int* qsrow = q_s + (size_t)(bh*TN + t0 + ln)*16;
        #pragma unroll
        for (int kc=0; kc<2; ++kc){
            int gi = kc*8 + qd4*2;
            dig16(qrow + kc*64 + qd4*16, qsrow[gi], qsrow[gi+1], qfh[kc], qfl[kc]);
        }
    }

    int scv[16][4];   // C[s][t]: s = (ch*8 + w*2 + i)*16 + qd4*4 + r, t = ln

    // ========== phase 1: QK^T scores, transposed (barrier-free, exact int) ==========
    // Tile ping-pong: prefetch tile t+1's 4 kd fragments while tile t computes.
    const v4i* kb_ = (const v4i*)(kd + (size_t)bh*KD_BH);
    if (PK){
        v4i fb[2][4];    // [parity][kc*2 + plane]
        {   // prologue: tile 0 (ch=0, i=0)
            const v4i* ta = kb_ + (w*2)*256 + lane;
            fb[0][0]=ta[0]; fb[0][1]=ta[64]; fb[0][2]=ta[128]; fb[0][3]=ta[192];
        }
        #pragma unroll
        for (int t=0; t<16; ++t){
            const int par = t & 1;
            if (t < 15){
                const int ch1 = (t+1)>>1, i1 = (t+1)&1;
                const v4i* ta = kb_ + (ch1*8 + w*2 + i1)*256 + lane;
                fb[par^1][0]=ta[0];   fb[par^1][1]=ta[64];
                fb[par^1][2]=ta[128]; fb[par^1][3]=ta[192];
            }
            v4i a2{0,0,0,0}, a1{0,0,0,0}, a0{0,0,0,0};
            #pragma unroll
            for (int kc=0;kc<2;kc++){
                v4i bhv = fb[par][kc*2], blv = fb[par][kc*2+1];
                a2 = __builtin_amdgcn_mfma_i32_16x16x64_i8(bhv, qfh[kc], a2, 0,0,0);
                a1 = __builtin_amdgcn_mfma_i32_16x16x64_i8(bhv, qfl[kc], a1, 0,0,0);
                a1 = __builtin_amdgcn_mfma_i32_16x16x64_i8(blv, qfh[kc], a1, 0,0,0);
                a0 = __builtin_amdgcn_mfma_i32_16x16x64_i8(blv, qfl[kc], a0, 0,0,0);
            }
            #pragma unroll
            for (int r=0;r<4;r++)
                scv[t][r] = (a2[r]<<8) + (a1[r]<<4) + a0[r];
        }
    } else {
        for (int ch=0; ch<8; ++ch){
            #pragma unroll
            for (int i=0;i<2;i++){
                const int n = w*2 + i;
                v4i a2{0,0,0,0}, a1{0,0,0,0}, a0{0,0,0,0};
                #pragma unroll
                for (int kc=0;kc<2;kc++){
                    int srow = bh*SN + ch*128 + n*16 + ln;
                    int cc   = kc*64 + qd4*16;
                    v4i bhv, blv;
                    dig16(k_q + (size_t)srow*128 + cc,
                          k_s[srow*16 + (cc>>3)], k_s[srow*16 + (cc>>3) + 1], bhv, blv);
                    a2 = __builtin_amdgcn_mfma_i32_16x16x64_i8(bhv, qfh[kc], a2, 0,0,0);
                    a1 = __builtin_amdgcn_mfma_i32_16x16x64_i8(bhv, qfl[kc], a1, 0,0,0);
                    a1 = __builtin_amdgcn_mfma_i32_16x16x64_i8(blv, qfh[kc], a1, 0,0,0);
                    a0 = __builtin_amdgcn_mfma_i32_16x16x64_i8(blv, qfl[kc], a0, 0,0,0);
                }
                int st = ch*2 + i;
                #pragma unroll
                for (int r=0;r<4;r++)
                    scv[st][r] = (a2[r]<<8) + (a1[r]<<4) + a0[r];
            }
        }
    }

    // ================= softmax over s (int-domain max, log2-domain exp) =================
    const float CS2 = (float)(6.103515625e-05 / 11.313708498984760390566
                              * 1.4426950408889634074);
    {
        int m0=-2147483647, m1=-2147483647, m2=-2147483647, m3=-2147483647;
        #pragma unroll
        for (int st=0;st<16;st++){
            m0 = max(m0, scv[st][0]);
            m1 = max(m1, scv[st][1]);
            m2 = max(m2, scv[st][2]);
            m3 = max(m3, scv[st][3]);
        }
        int m_ = max(max(m0,m1), max(m2,m3));
        m_ = max(m_, __shfl_xor(m_, 16));
        m_ = max(m_, __shfl_xor(m_, 32));
        if ((tid & 48) == 0) redi[w*16 + ln] = m_;
    }
    __syncthreads();                                  // bar1: redi visible
    float inv14;
    {
        const int mrow = max(max(redi[ln], redi[16+ln]), max(redi[32+ln], redi[48+ln]));
        float s0=0.f, s1=0.f, s2=0.f, s3=0.f;
        #pragma unroll
        for (int st=0;st<16;st++){
            #pragma unroll
            for (int r=0;r<4;r++){
                float t_ = (float)(scv[st][r] - mrow) * CS2;   // <= 0, diff exact in i32
                float e;
                asm("v_exp_f32 %0, %1" : "=v"(e) : "v"(t_));   // 2^t
                scv[st][r] = __float_as_int(e);
                if (r==0) s0 += e; else if (r==1) s1 += e; else if (r==2) s2 += e; else s3 += e;
            }
        }
        float s_ = (s0+s1) + (s2+s3);
        s_ += __shfl_xor(s_, 16);
        s_ += __shfl_xor(s_, 32);
        if ((tid & 48) == 0) redf[w*16 + ln] = s_;
    }
    __syncthreads();                                  // bar2: redf visible
    {
        float sum = redf[ln] + redf[16+ln] + redf[32+ln] + redf[48+ln];
        inv14 = 16384.0f / sum;        // one IEEE div per thread
    }
    __syncthreads();                                  // bar3: sum-reads done before
                                                      // requant overwrites row 15

    // ---- T14 async-stage: issue phase-2 group-0 vd loads NOW; their ~200cyc
    // L2 latency hides under the requant VALU below. (Independent of rbuf.)
    const v4i* vb = (const v4i*)(vd + (size_t)bh*VD_BH);
    v4i gb[2][8];    // [parity][2 per kb x 4 kb]
    v8s ga[2][4];
    if (PK){
        #pragma unroll
        for (int j=0;j<4;j++){
            gb[0][j*2]   = vb[(j*8 + w*2    )*64 + lane];
            gb[0][j*2+1] = vb[(j*8 + w*2 + 1)*64 + lane];
        }
    }

    // ======== group-of-8 po2 requant, in registers -> b64 rbuf stores ========
    // granule = thread's 4 s-values + partner at lane^16; gmax <= 255<<sh so no clamp.
    // XOR swizzle c' = c ^ ((ln&7)<<4) on unpadded 2048B rows (R13-validated).
    {
        const int lnr4 = (ln & 7) << 4;
        const int cbase = w*32 + qd4*4;
        unsigned short* rp = rbuf + ln*1024;
        #pragma unroll
        for (int st=0;st<16;st++){
            float v0 = rintf(__int_as_float(scv[st][0]) * inv14);
            float v1 = rintf(__int_as_float(scv[st][1]) * inv14);
            float v2 = rintf(__int_as_float(scv[st][2]) * inv14);
            float v3 = rintf(__int_as_float(scv[st][3]) * inv14);
            float g = fmaxf(fmaxf(v0,v1), fmaxf(v2,v3));
            g = fmaxf(g, __shfl_xor(g, 16));            // partner half of the granule
            int gi = max((int)g, 1);
            int x  = gi - 1;
            int e2 = 31 - __clz(x | 255);
            int sh = (e2 - 7) + ((x >> (e2 - 7)) == 255); // clip(ceil(log2(gi/255)),0,)
            float isc = __int_as_float((127 - sh) << 23); // exact 2^-sh
            float fsc = __int_as_float((127 + sh) << 23); // exact 2^sh
            unsigned b0 = __float_as_uint(rintf(v0*isc) * fsc);  // r = rq<<sh, 8 sig bits
            unsigned b1 = __float_as_uint(rintf(v1*isc) * fsc);
            unsigned b2 = __float_as_uint(rintf(v2*isc) * fsc);
            unsigned b3 = __float_as_uint(rintf(v3*isc) * fsc);
            unsigned w0 = __builtin_amdgcn_perm(b1, b0, 0x07060302u); // {bf16(v0),bf16(v1)}
            unsigned w1 = __builtin_amdgcn_perm(b3, b2, 0x07060302u);
            int c0 = (st>>1)*128 + cbase + (st&1)*16;   // col of v0 (u16 units, 4-aligned)
            *(v2u*)(rp + (c0 ^ lnr4)) = v2u{w0, w1};    // one swizzled b64 store per tile
        }
    }
    __syncthreads();                                  // bar4: rbuf ready

    // ================= phase 2: out = r @ vt^T (bf16 MFMA, barrier-free) =================
    // Group-of-4 ping-pong: prefetch group g+1's 8 vd loads + 4 LDS reads while
    // computing group g's 8 MFMAs.
    const unsigned short* rp2 = rbuf + ln*1024;
    const int lnr4b = (ln & 7) << 4;
    v4f acc0{0,0,0,0}, acc1{0,0,0,0};
    if (PK){
        #pragma unroll
        for (int j=0;j<4;j++)
            ga[0][j] = *(const v8s*)(rp2 + ((j*32 + qd4*8) ^ lnr4b));
        #pragma unroll
        for (int g=0; g<8; ++g){
            const int par = g & 1;
            if (g < 7){
                #pragma unroll
                for (int j=0;j<4;j++){
                    int kb = (g+1)*4 + j;
                    gb[par^1][j*2]   = vb[(kb*8 + w*2    )*64 + lane];
                    gb[par^1][j*2+1] = vb[(kb*8 + w*2 + 1)*64 + lane];
                    ga[par^1][j] = *(const v8s*)(rp2 + ((kb*32 + qd4*8) ^ lnr4b));
                }
            }
            #pragma unroll
            for (int j=0;j<4;j++){
                v8s bs0, bs1;
                memcpy(&bs0, &gb[par][j*2],   16);
                memcpy(&bs1, &gb[par][j*2+1], 16);
                acc0 = __builtin_amdgcn_mfma_f32_16x16x32_bf16(ga[par][j], bs0, acc0, 0,0,0);
                acc1 = __builtin_amdgcn_mfma_f32_16x16x32_bf16(ga[par][j], bs1, acc1, 0,0,0);
            }
        }
    } else {
        #pragma unroll 4
        for (int kb=0; kb<32; ++kb){
            v8s af = *(const v8s*)(rp2 + ((kb*32 + qd4*8) ^ lnr4b));
            v4i b0, b1;
            #pragma unroll
            for (int i=0;i<2;i++){
                int chan = (w*2+i)*16 + ln;
                const int* vp = vt_q + (size_t)(bh*HCN + chan)*SN + kb*32 + qd4*8;
                int s = vt_s[(bh*HCN + chan)*128 + kb*4 + qd4];
                unsigned wd[4];
                #pragma unroll
                for (int j=0;j<4;j++){
                    int a = vp[j*2]   << s;
                    int b = vp[j*2+1] << s;
                    wd[j] = (unsigned)bf16_of_int(a) | ((unsigned)bf16_of_int(b)<<16);
                }
                v4i t{(int)wd[0],(int)wd[1],(int)wd[2],(int)wd[3]};
                if (i==0) b0 = t; else b1 = t;
            }
            v8s bs0, bs1;
            memcpy(&bs0, &b0, 16);
            memcpy(&bs1, &b1, 16);
            acc0 = __builtin_amdgcn_mfma_f32_16x16x32_bf16(af, bs0, acc0, 0,0,0);
            acc1 = __builtin_amdgcn_mfma_f32_16x16x32_bf16(af, bs1, acc1, 0,0,0);
        }
    }
    #pragma unroll
    for (int r=0;r<4;r++){
        size_t o = (size_t)(bh*TN + t0 + qd4*4 + r)*HCN + w*32 + ln;
        out[o]      = (int)rintf(acc0[r]);
        out[o + 16] = (int)rintf(acc1[r]);
    }
}

extern "C" void kernel_launch(void* const* d_in, const int* in_sizes, int n_in,
                              void* d_out, int out_size, void* d_ws, size_t ws_size,
                              hipStream_t stream) {
    const int* q_q  = (const int*)d_in[0];
    const int* q_s  = (const int*)d_in[1];
    const int* k_q  = (const int*)d_in[2];
    const int* k_s  = (const int*)d_in[3];
    const int* vt_q = (const int*)d_in[4];
    const int* vt_s = (const int*)d_in[5];
    int* out = (int*)d_out;

    unsigned char* kd = (unsigned char*)d_ws;
    unsigned char* vd = kd + (size_t)BHN*KD_BH;

    if (ws_size >= WS_NEED){
        // 12288 wave-tasks (4096 kd + 8192 vd), 4 waves/block
        digitize<<<dim3(3072), 256, 0, stream>>>(k_q,k_s,vt_q,vt_s, kd,vd);
        mha_mfma<true><<<dim3(2048), 256, 0, stream>>>(
            q_q,q_s,k_q,k_s,vt_q,vt_s, kd,vd, out);
    } else {
        mha_mfma<false><<<dim3(2048), 256, 0, stream>>>(
            q_q,q_s,k_q,k_s,vt_q,vt_s, kd,vd, out);
    }
}

// Round 10
// 146.844 us; speedup vs baseline: 1.0535x; 1.0259x over previous
//
#include <hip/hip_runtime.h>
#include <string.h>

// Integer-quantized MHA. R18: bf16 phase-1 (R14's work reduction) + COMPILER-
// PROOF prefetch (sched_barrier(0) fences; the R16 lesson).
// Evidence chain:
//  - R14: bf16 phase-1 halves MFMA + deletes 256 recombine-VALU/thread; busy
//    time fell but stall +45k cyc -> load-latency exposed -> 72.5us.
//  - R16: source-level ping-pong on i8 path: VGPR stayed 68 (< scv+fb+qf=115)
//    => compiler SANK the prefetch loads to use sites (rule-18 behavior);
//    null result (61us). Prefetch was never actually tested.
//  - R18: issue tile t+1 loads, then __builtin_amdgcn_sched_barrier(0), then
//    tile t MFMAs: loads pinned before compute, auto-waitcnt becomes counted
//    vmcnt(4) -> loads in flight across compute (T3/T4). Same in phase 2 and
//    for the requant-hoisted vd group-0 loads (T14).
// Phase 1 math = R14 (bf16 exact: K/Q values <=8 sig bits; products exact in
// f32; scores sigma~1.3e6 << 2^24). Softmax float-domain = R14. Requant/XOR
// swizzle/32KB LDS/barriers = R13. Phase-2 ping = R16. launch_bounds(256,3)
// (VGPR cap 170; expect ~120-150 with REAL prefetch -- VGPR<=80 means defeated).
// Closed axes: TT=32 (R9/R12), LDS conflicts (R4/R5), LDS-size occupancy (R7),
// bf16-without-prefetch (R14), source-level-prefetch-without-fence (R16).
// B=2,H=16 (BH=32), T=S=1024, HC=128, G=8. Output int32.

typedef int   v4i __attribute__((ext_vector_type(4)));
typedef float v4f __attribute__((ext_vector_type(4)));
typedef short v8s __attribute__((ext_vector_type(8)));
typedef unsigned v2u __attribute__((ext_vector_type(2)));

#define BHN 32
#define TN  1024
#define SN  1024
#define HCN 128
#define TT  16
#define KD_BH 262144           // 8 ch * 8 n * 4 kc * 64 lanes * 16 B (bf16 frags)
#define VD_BH 262144           // 32 kb * 8 n * 64 lanes * 16 B (bf16 frags)
#define WS_NEED ((size_t)BHN*(KD_BH+VD_BH))   // 16 MB

__device__ __forceinline__ unsigned short bf16_of_int(int v){
    return (unsigned short)(__float_as_uint((float)v) >> 16);   // exact: <=8 sig bits
}

// pack 8 consecutive dequantized ints (one scale group) into 4 bf16x2 words
__device__ __forceinline__ v4i pack8(const int* __restrict__ p, int s){
    unsigned wd[4];
    #pragma unroll
    for (int j=0;j<4;j++){
        int a = p[j*2]   << s;
        int b = p[j*2+1] << s;
        wd[j] = (unsigned)bf16_of_int(a) | ((unsigned)bf16_of_int(b) << 16);
    }
    return v4i{(int)wd[0],(int)wd[1],(int)wd[2],(int)wd[3]};
}

// ---------------- pre-pass (gather form: coalesced stores) ----------------
// kd: per bh, [ch(8)][n(8)][kc(4)][lane64][16B] bf16 A-frags (K=32 chunks):
//     lane q4*16+l15 holds K[row=n*16+l15][c = kc*32 + q4*8 + 0..7].
// vd: per bh, [kb(32)][n(8)][lane64][16B] bf16 B-frags.
// One wave per fragment tile: lane stores base+lane*16 -> 1KB wave-stores.
// Tasks: 0..8191 = kd (bh*256+ch*32+n*4+kc); 8192..16383 = vd (bh*256+kb*8+n).
__global__ __launch_bounds__(256) void digitize(
    const int* __restrict__ k_q, const int* __restrict__ k_s,
    const int* __restrict__ vt_q, const int* __restrict__ vt_s,
    unsigned char* __restrict__ kd, unsigned char* __restrict__ vd)
{
    const int w    = threadIdx.x >> 6;
    const int lane = threadIdx.x & 63;
    const int l15  = lane & 15;
    const int q4   = lane >> 4;
    const int task = blockIdx.x*4 + w;
    if (task < 8192){
        const int kc = task & 3, n = (task>>2)&7, ch = (task>>5)&7, bh = task>>8;
        const int row = bh*SN + ch*128 + n*16 + l15;
        const int col = kc*32 + q4*8;
        v4i f = pack8(k_q + (size_t)row*HCN + col, k_s[row*16 + (col>>3)]);
        size_t base = (size_t)bh*KD_BH + (size_t)((((ch*8+n)*4 + kc)*64 + lane)*16);
        *(v4i*)(kd + base) = f;             // 1KB coalesced wave store
    } else {
        const int t  = task - 8192;
        const int n  = t & 7, kb = (t>>3)&31, bh = t>>8;
        const int row = bh*HCN + n*16 + l15;       // vt channel row
        v4i f = pack8(vt_q + (size_t)row*SN + kb*32 + q4*8,
                      vt_s[row*128 + kb*4 + q4]);
        size_t base = (size_t)bh*VD_BH + (size_t)(((kb*8 + n)*64 + lane)*16);
        *(v4i*)(vd + base) = f;
    }
}

// ---------------- main fused kernel ----------------
template<bool PK>
__global__ __launch_bounds__(256,3) void mha_mfma(
    const int* __restrict__ q_q, const int* __restrict__ q_s,
    const int* __restrict__ k_q, const int* __restrict__ k_s,
    const int* __restrict__ vt_q, const int* __restrict__ vt_s,
    const unsigned char* __restrict__ kd, const unsigned char* __restrict__ vd,
    int* __restrict__ out)
{
    // EXACTLY 32 KB (R13 artifact).
    __shared__ __align__(16) unsigned short rbuf[16*1024];
    // reduction scratch carved into rbuf row 15 cols 768..1023 (dead until
    // requant, which overwrites it only after bar3).
    float* redm = (float*)(rbuf + 16128);   // 64 floats: row-max partials
    float* redf = (float*)(rbuf + 16256);   // 64 floats: row-sum partials

    const int tid  = threadIdx.x;
    const int ln   = tid & 15;
    const int qd4  = (tid >> 4) & 3;
    const int w    = tid >> 6;
    const int lane = tid & 63;
    // XCD-aware swizzle: each XCD's share covers only 4 bh -> digit images fit its L2.
    const int blk = blockIdx.x;
    const int bh  = ((blk>>9)<<3) | (blk&7);
    const int t0  = ((blk>>3)&63) * TT;

    // ---- Q fragments in registers (B operand in phase 1, t=ln), bf16 exact ----
    v8s qf[4];
    {
        const int* qrow = q_q + (size_t)(bh*TN + t0 + ln)*HCN;
        const int* qs   = q_s + (size_t)(bh*TN + t0 + ln)*16;
        #pragma unroll
        for (int kc=0; kc<4; ++kc){
            int col = kc*32 + qd4*8;
            v4i t = pack8(qrow + col, qs[col>>3]);
            memcpy(&qf[kc], &t, 16);
        }
    }

    v4f scv[16];   // C[s][t]: s = (ch*8 + w*2 + i)*16 + qd4*4 + r, t = ln
                   // EXACT integer scores in f32 (see header)

    // ========== phase 1: QK^T, transposed bf16 MFMA, fenced ping-pong ==========
    const v4i* kb_ = (const v4i*)(kd + (size_t)bh*KD_BH);
    if (PK){
        v4i fb[2][4];    // [parity][kc] -- one tile = 4 fragments
        {   // prologue: tile 0 (ch=0, i=0, n=w*2)
            const v4i* ta = kb_ + ((w*2)*4)*64 + lane;
            fb[0][0]=ta[0]; fb[0][1]=ta[64]; fb[0][2]=ta[128]; fb[0][3]=ta[192];
        }
        #pragma unroll
        for (int t=0; t<16; ++t){
            const int par = t & 1;
            if (t < 15){
                const int t1 = t+1, ch1 = t1>>1, i1 = t1&1;
                const v4i* ta = kb_ + ((ch1*8 + w*2 + i1)*4)*64 + lane;
                fb[par^1][0]=ta[0];   fb[par^1][1]=ta[64];
                fb[par^1][2]=ta[128]; fb[par^1][3]=ta[192];
            }
            // Pin: loads above issue BEFORE the MFMAs below -> counted vmcnt,
            // next tile's 4 loads stay in flight across this tile's compute.
            __builtin_amdgcn_sched_barrier(0);
            v4f acc{0.f,0.f,0.f,0.f};
            #pragma unroll
            for (int kc=0;kc<4;kc++){
                v8s af;
                memcpy(&af, &fb[par][kc], 16);
                acc = __builtin_amdgcn_mfma_f32_16x16x32_bf16(af, qf[kc], acc, 0,0,0);
            }
            scv[t] = acc;
        }
    } else {
        for (int ch=0; ch<8; ++ch){
            #pragma unroll
            for (int i=0;i<2;i++){
                const int n = w*2 + i;
                v4f acc{0.f,0.f,0.f,0.f};
                #pragma unroll
                for (int kc=0;kc<4;kc++){
                    int srow = bh*SN + ch*128 + n*16 + ln;
                    int cc   = kc*32 + qd4*8;
                    v4i a_ = pack8(k_q + (size_t)srow*HCN + cc,
                                   k_s[srow*16 + (cc>>3)]);
                    v8s af;
                    memcpy(&af, &a_, 16);
                    acc = __builtin_amdgcn_mfma_f32_16x16x32_bf16(af, qf[kc], acc, 0,0,0);
                }
                scv[ch*2 + i] = acc;
            }
        }
    }

    // ================= softmax over s (float max, log2-domain exp) =================
    // Scores are exact ints in f32; (s - m) subtraction exact at these magnitudes.
    const float CS2 = (float)(6.103515625e-05 / 11.313708498984760390566
                              * 1.4426950408889634074);
    {
        float m0=-3.0e38f, m1=-3.0e38f, m2=-3.0e38f, m3=-3.0e38f;
        #pragma unroll
        for (int st=0;st<16;st++){
            m0 = fmaxf(m0, scv[st][0]);
            m1 = fmaxf(m1, scv[st][1]);
            m2 = fmaxf(m2, scv[st][2]);
            m3 = fmaxf(m3, scv[st][3]);
        }
        float m_ = fmaxf(fmaxf(m0,m1), fmaxf(m2,m3));
        m_ = fmaxf(m_, __shfl_xor(m_, 16));
        m_ = fmaxf(m_, __shfl_xor(m_, 32));
        if ((tid & 48) == 0) redm[w*16 + ln] = m_;
    }
    __syncthreads();                                  // bar1: redm visible
    float inv14;
    {
        const float mrow = fmaxf(fmaxf(redm[ln], redm[16+ln]),
                                 fmaxf(redm[32+ln], redm[48+ln]));
        float s0=0.f, s1=0.f, s2=0.f, s3=0.f;
        #pragma unroll
        for (int st=0;st<16;st++){
            #pragma unroll
            for (int r=0;r<4;r++){
                float t_ = (scv[st][r] - mrow) * CS2;          // <= 0, sub exact
                float e;
                asm("v_exp_f32 %0, %1" : "=v"(e) : "v"(t_));   // 2^t
                scv[st][r] = e;
                if (r==0) s0 += e; else if (r==1) s1 += e; else if (r==2) s2 += e; else s3 += e;
            }
        }
        float s_ = (s0+s1) + (s2+s3);
        s_ += __shfl_xor(s_, 16);
        s_ += __shfl_xor(s_, 32);
        if ((tid & 48) == 0) redf[w*16 + ln] = s_;
    }
    __syncthreads();                                  // bar2: redf visible
    {
        float sum = redf[ln] + redf[16+ln] + redf[32+ln] + redf[48+ln];
        inv14 = 16384.0f / sum;        // one IEEE div per thread
    }
    __syncthreads();                                  // bar3: sum-reads done before
                                                      // requant overwrites row 15

    // ---- T14 async-stage: issue phase-2 group-0 vd loads NOW, fenced so they
    // can't sink; ~200cyc L2 latency hides under the requant VALU below.
    const v4i* vb = (const v4i*)(vd + (size_t)bh*VD_BH);
    v4i gb[2][8];
    v8s ga[2][4];
    if (PK){
        #pragma unroll
        for (int j=0;j<4;j++){
            gb[0][j*2]   = vb[(j*8 + w*2    )*64 + lane];
            gb[0][j*2+1] = vb[(j*8 + w*2 + 1)*64 + lane];
        }
        __builtin_amdgcn_sched_barrier(0);
    }

    // ======== group-of-8 po2 requant, in registers -> b64 rbuf stores ========
    // granule = thread's 4 s-values + partner at lane^16; gmax <= 255<<sh so no clamp.
    // XOR swizzle c' = c ^ ((ln&7)<<4) on unpadded 2048B rows (R13-validated).
    {
        const int lnr4 = (ln & 7) << 4;
        const int cbase = w*32 + qd4*4;
        unsigned short* rp = rbuf + ln*1024;
        #pragma unroll
        for (int st=0;st<16;st++){
            float v0 = rintf(scv[st][0] * inv14);
            float v1 = rintf(scv[st][1] * inv14);
            float v2 = rintf(scv[st][2] * inv14);
            float v3 = rintf(scv[st][3] * inv14);
            float g = fmaxf(fmaxf(v0,v1), fmaxf(v2,v3));
            g = fmaxf(g, __shfl_xor(g, 16));            // partner half of the granule
            int gi = max((int)g, 1);
            int x  = gi - 1;
            int e2 = 31 - __clz(x | 255);
            int sh = (e2 - 7) + ((x >> (e2 - 7)) == 255); // clip(ceil(log2(gi/255)),0,)
            float isc = __int_as_float((127 - sh) << 23); // exact 2^-sh
            float fsc = __int_as_float((127 + sh) << 23); // exact 2^sh
            unsigned b0 = __float_as_uint(rintf(v0*isc) * fsc);  // r = rq<<sh, 8 sig bits
            unsigned b1 = __float_as_uint(rintf(v1*isc) * fsc);
            unsigned b2 = __float_as_uint(rintf(v2*isc) * fsc);
            unsigned b3 = __float_as_uint(rintf(v3*isc) * fsc);
            unsigned w0 = __builtin_amdgcn_perm(b1, b0, 0x07060302u); // {bf16(v0),bf16(v1)}
            unsigned w1 = __builtin_amdgcn_perm(b3, b2, 0x07060302u);
            int c0 = (st>>1)*128 + cbase + (st&1)*16;   // col of v0 (u16 units, 4-aligned)
            *(v2u*)(rp + (c0 ^ lnr4)) = v2u{w0, w1};    // one swizzled b64 store per tile
        }
    }
    __syncthreads();                                  // bar4: rbuf ready

    // ================= phase 2: out = r @ vt^T (bf16 MFMA, fenced ping-pong) =========
    const unsigned short* rp2 = rbuf + ln*1024;
    const int lnr4b = (ln & 7) << 4;
    v4f acc0{0,0,0,0}, acc1{0,0,0,0};
    if (PK){
        #pragma unroll
        for (int j=0;j<4;j++)
            ga[0][j] = *(const v8s*)(rp2 + ((j*32 + qd4*8) ^ lnr4b));
        #pragma unroll
        for (int g=0; g<8; ++g){
            const int par = g & 1;
            if (g < 7){
                #pragma unroll
                for (int j=0;j<4;j++){
                    int kb = (g+1)*4 + j;
                    gb[par^1][j*2]   = vb[(kb*8 + w*2    )*64 + lane];
                    gb[par^1][j*2+1] = vb[(kb*8 + w*2 + 1)*64 + lane];
                    ga[par^1][j] = *(const v8s*)(rp2 + ((kb*32 + qd4*8) ^ lnr4b));
                }
            }
            __builtin_amdgcn_sched_barrier(0);        // pin loads before MFMAs
            #pragma unroll
            for (int j=0;j<4;j++){
                v8s bs0, bs1;
                memcpy(&bs0, &gb[par][j*2],   16);
                memcpy(&bs1, &gb[par][j*2+1], 16);
                acc0 = __builtin_amdgcn_mfma_f32_16x16x32_bf16(ga[par][j], bs0, acc0, 0,0,0);
                acc1 = __builtin_amdgcn_mfma_f32_16x16x32_bf16(ga[par][j], bs1, acc1, 0,0,0);
            }
        }
    } else {
        #pragma unroll 4
        for (int kb=0; kb<32; ++kb){
            v8s af = *(const v8s*)(rp2 + ((kb*32 + qd4*8) ^ lnr4b));
            v4i b0, b1;
            #pragma unroll
            for (int i=0;i<2;i++){
                int chan = (w*2+i)*16 + ln;
                v4i t = pack8(vt_q + (size_t)(bh*HCN + chan)*SN + kb*32 + qd4*8,
                              vt_s[(bh*HCN + chan)*128 + kb*4 + qd4]);
                if (i==0) b0 = t; else b1 = t;
            }
            v8s bs0, bs1;
            memcpy(&bs0, &b0, 16);
            memcpy(&bs1, &b1, 16);
            acc0 = __builtin_amdgcn_mfma_f32_16x16x32_bf16(af, bs0, acc0, 0,0,0);
            acc1 = __builtin_amdgcn_mfma_f32_16x16x32_bf16(af, bs1, acc1, 0,0,0);
        }
    }
    #pragma unroll
    for (int r=0;r<4;r++){
        size_t o = (size_t)(bh*TN + t0 + qd4*4 + r)*HCN + w*32 + ln;
        out[o]      = (int)rintf(acc0[r]);
        out[o + 16] = (int)rintf(acc1[r]);
    }
}

extern "C" void kernel_launch(void* const* d_in, const int* in_sizes, int n_in,
                              void* d_out, int out_size, void* d_ws, size_t ws_size,
                              hipStream_t stream) {
    const int* q_q  = (const int*)d_in[0];
    const int* q_s  = (const int*)d_in[1];
    const int* k_q  = (const int*)d_in[2];
    const int* k_s  = (const int*)d_in[3];
    const int* vt_q = (const int*)d_in[4];
    const int* vt_s = (const int*)d_in[5];
    int* out = (int*)d_out;

    unsigned char* kd = (unsigned char*)d_ws;
    unsigned char* vd = kd + (size_t)BHN*KD_BH;

    if (ws_size >= WS_NEED){
        // 16384 wave-tasks (8192 kd + 8192 vd), 4 waves/block
        digitize<<<dim3(4096), 256, 0, stream>>>(k_q,k_s,vt_q,vt_s, kd,vd);
        mha_mfma<true><<<dim3(2048), 256, 0, stream>>>(
            q_q,q_s,k_q,k_s,vt_q,vt_s, kd,vd, out);
    } else {
        mha_mfma<false><<<dim3(2048), 256, 0, stream>>>(
            q_q,q_s,k_q,k_s,vt_q,vt_s, kd,vd, out);
    }
}